// Round 2
// baseline (493.917 us; speedup 1.0000x reference)
//
#include <hip/hip_runtime.h>

#define ROWS 8192
#define COLS 8192
#define TPB  256
#define VPT  8            // float4 chunks per thread (32 elements)
#define NBINS 1024        // 10-bit first-pass histogram
#define SHIFT 22          // key >> 22 = top 10 bits
#define CAND_CAP 1024     // candidate buffer (aliases sHist, 4 KB)

// Monotonic float->uint key: order of keys == order of floats.
__device__ __forceinline__ unsigned f2k(float x) {
    unsigned u = __float_as_uint(x);
    return (u & 0x80000000u) ? ~u : (u | 0x80000000u);
}
__device__ __forceinline__ float k2f(unsigned k) {
    unsigned u = (k & 0x80000000u) ? (k & 0x7FFFFFFFu) : ~k;
    return __uint_as_float(u);
}

__global__ __launch_bounds__(TPB, 4)
void rsoftmax_kernel(const float* __restrict__ in,
                     const float* __restrict__ rate_p,
                     float* __restrict__ out)
{
    const int t    = threadIdx.x;
    const int lane = t & 63;
    const int wv   = t >> 6;
    const int row  = blockIdx.x;

    __shared__ __align__(16) unsigned sKeys[COLS];   // 32 KB: staged keys, later products
    __shared__ __align__(16) unsigned sHist[NBINS];  // 4 KB: histogram, reused as candidates
    __shared__ unsigned sWaveTot[4];
    __shared__ unsigned sBin, sR, sC, sNc, sThrKey;
    __shared__ float    sRed[4];
    unsigned* sCand = sHist;                          // alias: hist dead after scan

    // ---- rank: thresh = sorted_desc[idx] == (idx+1)-th largest ----
    float rate = rate_p[0];
    rate = fminf(fmaxf(rate, 0.0f), 1.0f);
    int idx = (int)(rate * (float)COLS);             // trunc like astype(int32)
    if (idx > COLS - 1) idx = COLS - 1;              // jnp.take clips
    const unsigned k = (unsigned)(idx + 1);

    // ---- clear histogram + counters ----
    ((uint4*)sHist)[t] = make_uint4(0u, 0u, 0u, 0u);
    if (t == 0) sNc = 0u;
    __syncthreads();

    // ---- load + convert + stage to LDS + 10-bit histogram, single pass ----
    const float4* in4 = (const float4*)(in + (size_t)row * COLS);
    #pragma unroll
    for (int j = 0; j < VPT; ++j) {
        float4 v = in4[t + j * TPB];                 // coalesced 16B/lane
        unsigned k0 = f2k(v.x), k1 = f2k(v.y), k2 = f2k(v.z), k3 = f2k(v.w);
        ((uint4*)sKeys)[t + j * TPB] = make_uint4(k0, k1, k2, k3);
        atomicAdd(&sHist[k0 >> SHIFT], 1u);
        atomicAdd(&sHist[k1 >> SHIFT], 1u);
        atomicAdd(&sHist[k2 >> SHIFT], 1u);
        atomicAdd(&sHist[k3 >> SHIFT], 1u);
    }
    __syncthreads();

    // ---- hierarchical suffix scan over 1024 bins; locate bin of rank k ----
    uint4 h4 = ((uint4*)sHist)[t];                   // thread owns bins 4t..4t+3
    unsigned L = h4.x + h4.y + h4.z + h4.w;
    unsigned W = L;                                  // inclusive suffix within wave
    #pragma unroll
    for (int off = 1; off < 64; off <<= 1) {
        unsigned o = __shfl(W, lane + off, 64);
        W += (lane + off < 64) ? o : 0u;
    }
    if (lane == 0) sWaveTot[wv] = W;                 // wave total
    __syncthreads();
    unsigned above = W - L;                          // strictly-above within wave
    #pragma unroll
    for (int w = 0; w < 4; ++w)
        if (w > wv) above += sWaveTot[w];
    {
        unsigned hh[4] = {h4.x, h4.y, h4.z, h4.w};
        unsigned nxt = above;                        // S[4t+4]
        #pragma unroll
        for (int j = 3; j >= 0; --j) {               // descending: S[b] >= k > S[b+1]
            unsigned cur = nxt + hh[j];
            if (cur >= k && nxt < k) {
                sBin = (unsigned)(4 * t + j);
                sR   = k - nxt;                      // rank within bin
                sC   = hh[j];                        // candidate count
            }
            nxt = cur;
        }
    }
    __syncthreads();

    const unsigned bin = sBin;
    const unsigned C   = sC;
    const unsigned lo0 = bin << SHIFT;

    if (C <= CAND_CAP) {
        // ---- compact candidates (typ. ~10-50 for normal data) ----
        #pragma unroll
        for (int j = 0; j < VPT; ++j) {
            uint4 kk = ((uint4*)sKeys)[t + j * TPB];
            unsigned ka[4] = {kk.x, kk.y, kk.z, kk.w};
            #pragma unroll
            for (int q = 0; q < 4; ++q) {
                if ((ka[q] >> SHIFT) == bin) {
                    unsigned pos = atomicAdd(&sNc, 1u);
                    sCand[pos] = ka[q];
                }
            }
        }
        __syncthreads();
        // ---- wave 0: bisect remaining 22 bits, ballot-count, no barriers ----
        if (wv == 0) {
            unsigned lo = lo0, hi = lo0 | ((1u << SHIFT) - 1u);
            const unsigned r = sR;
            while (lo < hi) {
                unsigned mid = lo + ((hi - lo) >> 1) + 1u;
                unsigned c = 0;
                for (unsigned i = (unsigned)lane; i < C; i += 64u)
                    c += (sCand[i] >= mid) ? 1u : 0u;
                #pragma unroll
                for (int off = 32; off > 0; off >>= 1)
                    c += __shfl_xor(c, off, 64);
                if (c >= r) lo = mid; else hi = mid - 1u;
            }
            if (lane == 0) sThrKey = lo;
        }
        __syncthreads();
    } else {
        // ---- fallback (degenerate dup-heavy data): block-wide bisection ----
        unsigned lo = lo0, hi = lo0 | ((1u << SHIFT) - 1u);
        while (lo < hi) {                            // block-uniform trip count
            unsigned mid = lo + ((hi - lo) >> 1) + 1u;
            unsigned c = 0;
            #pragma unroll
            for (int j = 0; j < VPT; ++j) {
                uint4 kk = ((uint4*)sKeys)[t + j * TPB];
                c += (kk.x >= mid) + (kk.y >= mid) + (kk.z >= mid) + (kk.w >= mid);
            }
            #pragma unroll
            for (int off = 32; off > 0; off >>= 1)
                c += __shfl_xor(c, off, 64);
            if (lane == 0) sWaveTot[wv] = c;
            __syncthreads();
            c = sWaveTot[0] + sWaveTot[1] + sWaveTot[2] + sWaveTot[3];
            if (c >= k) lo = mid; else hi = mid - 1u;
            __syncthreads();
        }
        if (t == 0) sThrKey = lo;
        __syncthreads();
    }

    // ---- products p = relu(x-thr)*exp(x); overwrite sKeys; partial sum ----
    const float thr = k2f(sThrKey);
    float lsum = 0.0f;
    #pragma unroll
    for (int j = 0; j < VPT; ++j) {
        uint4 kk = ((uint4*)sKeys)[t + j * TPB];
        float x0 = k2f(kk.x), x1 = k2f(kk.y), x2 = k2f(kk.z), x3 = k2f(kk.w);
        float p0 = fmaxf(x0 - thr, 0.0f) * __expf(x0);
        float p1 = fmaxf(x1 - thr, 0.0f) * __expf(x1);
        float p2 = fmaxf(x2 - thr, 0.0f) * __expf(x2);
        float p3 = fmaxf(x3 - thr, 0.0f) * __expf(x3);
        lsum += (p0 + p1) + (p2 + p3);
        ((uint4*)sKeys)[t + j * TPB] =
            make_uint4(__float_as_uint(p0), __float_as_uint(p1),
                       __float_as_uint(p2), __float_as_uint(p3));
    }
    #pragma unroll
    for (int off = 32; off > 0; off >>= 1)
        lsum += __shfl_xor(lsum, off, 64);
    if (lane == 0) sRed[wv] = lsum;
    __syncthreads();
    const float inv = 1.0f / (sRed[0] + sRed[1] + sRed[2] + sRed[3]);

    // ---- normalized write, float4-coalesced ----
    float4* out4 = (float4*)(out + (size_t)row * COLS);
    #pragma unroll
    for (int j = 0; j < VPT; ++j) {
        uint4 p4 = ((uint4*)sKeys)[t + j * TPB];
        float4 o;
        o.x = __uint_as_float(p4.x) * inv;
        o.y = __uint_as_float(p4.y) * inv;
        o.z = __uint_as_float(p4.z) * inv;
        o.w = __uint_as_float(p4.w) * inv;
        out4[t + j * TPB] = o;
    }
}

extern "C" void kernel_launch(void* const* d_in, const int* in_sizes, int n_in,
                              void* d_out, int out_size, void* d_ws, size_t ws_size,
                              hipStream_t stream)
{
    const float* in   = (const float*)d_in[0];
    const float* rate = (const float*)d_in[1];
    float*       out  = (float*)d_out;
    rsoftmax_kernel<<<dim3(ROWS), dim3(TPB), 0, stream>>>(in, rate, out);
}